// Round 8
// baseline (672.862 us; speedup 1.0000x reference)
//
#include <hip/hip_runtime.h>

// ReLU_Feat_Posenc: bilinear gather (512x512x100) + posenc(16 freq) + MLP 166->128x4->3
// R11: single-buffer k_main. R10's A/B: sort is ESSENTIAL (unsorted FETCH 133MB->995MB,
//      k_main 294->406) and ~100us of "aux" is harness fixed overhead (sort chain's true
//      cost is ~89us). k_main (294us) is latency-bound: MFMA 23 + VALU 47 = 70% busy,
//      occupancy 43% capped by LDS 40960B = 4 blocks/CU. Fix: drop bufB -- MLP runs
//      IN-PLACE in bufA (read-all -> barrier -> overwrite cols 0..127 -> barrier; X cols
//      0..127 are dead after each layer's reads). LDS 23552B -> 6 blocks/CU (24 waves).
//      oidx carried in a register (FE thread t>>2 == L4 thread t>>2). Swizzle dropped:
//      1.1e7 conflicts ~= 1.4 cyc/LDS-instr -- low EV. Math identical to green R9.

#define GN    512
#define TP    64    // points per tile
#define STR0  184   // LDS row stride (f16), row = 368 B; X cols 0..175, G cols 0..127

// wt fragment-order offsets (f16 elems)
#define WOFF1 22528
#define WOFF2 38912
#define WOFF3 55296
#define W4OFF 71680  // packed W4: [qt 0..3][kk 0..31][e 0..2] f16 (384 elems)

typedef _Float16 half8  __attribute__((ext_vector_type(8)));
typedef _Float16 half4v __attribute__((ext_vector_type(4)));
typedef float    f4     __attribute__((ext_vector_type(4)));
typedef float    f16v   __attribute__((ext_vector_type(16)));

// ws layout (bytes):
//   0         wt fragment-order f16 (+ packed W4) (reserve 147456)
//   147456    hist    int[16384]
//   212992    binoff  int[16384]
//   278528    bsum    int[64]
//   278784    bbase   int[64]
//   294912    sorted  float4[1048576] (16 MB)   total ~17 MB

// ---------- fused prep: weights+W4 pack | hist ----------
__global__ __launch_bounds__(256) void k_prep(
    const float* __restrict__ W0, const float* __restrict__ W1,
    const float* __restrict__ W2, const float* __restrict__ W3,
    const float* __restrict__ W4, _Float16* __restrict__ wt,
    const float* __restrict__ UV, int* __restrict__ hist) {
  int b = blockIdx.x;
  if (b < 282) {                     // ---- weights into MFMA-fragment order ----
    int t = b * 256 + threadIdx.x;
    if (t >= 72064) return;
    float v;
    if (t < 22528) {                 // L0 frags: ((ot*11+ks)*64+l)*8+j
      int j = t & 7, l = (t >> 3) & 63, g = t >> 9;
      int ks = g % 11;
      int ot = g / 11;
      int k = 16 * ks + 8 * (l >> 5) + j;     // X column
      int n = ot * 32 + (l & 31);             // out channel
      if (k < 100)      v = W0[(66 + k) * 128 + n];   // feat rows of W0
      else if (k < 166) v = W0[(k - 100) * 128 + n];  // UV + posenc rows
      else              v = 0.0f;                     // K pad 166..175
    } else if (t < 71680) {          // L1-3 frags
      int u = t - 22528;
      int layer = u >> 14, r = u & 16383;
      int j = r & 7, l = (r >> 3) & 63, ks = (r >> 9) & 7, ot = r >> 12;
      int k = 16 * ks + 8 * (l >> 5) + j;
      int n = ot * 32 + (l & 31);
      const float* W = (layer == 0) ? W1 : (layer == 1) ? W2 : W3;
      v = W[k * 128 + n];
    } else {                         // packed W4: wt[W4OFF + qt*96 + kk*3 + e]
      int u2 = t - 71680;            // 0..383
      int qt = u2 / 96, r = u2 - 96 * qt;
      int kk = r / 3, e = r - 3 * kk;
      v = W4[(qt * 32 + kk) * 3 + e];
    }
    wt[t] = (_Float16)v;
  } else if (hist != nullptr) {      // ---- histogram (hist pre-zeroed by memset) ----
    int i = (b - 282) * 256 + threadIdx.x;
    float2 uv = ((const float2*)UV)[i];
    int iU0 = (int)floorf(511.0f * uv.x);
    int iV0 = (int)floorf(511.0f * uv.y);
    atomicAdd(&hist[iU0 * 32 + (iV0 >> 4)], 1);
  }
}

__device__ __forceinline__ int point_bin(float U, float V) {
  int iU0 = (int)floorf(511.0f * U);
  int iV0 = (int)floorf(511.0f * V);
  return iU0 * 32 + (iV0 >> 4);
}

__global__ __launch_bounds__(256) void k_scanA(const int* __restrict__ hist,
                                               int* __restrict__ binoff,
                                               int* __restrict__ bsum) {
  __shared__ int s[256];
  int t = threadIdx.x, g = blockIdx.x * 256 + t;   // 64 blocks
  int v = hist[g];
  s[t] = v;
  __syncthreads();
  for (int d = 1; d < 256; d <<= 1) {
    int x = (t >= d) ? s[t - d] : 0;
    __syncthreads();
    s[t] += x;
    __syncthreads();
  }
  binoff[g] = s[t] - v;
  if (t == 255) bsum[blockIdx.x] = s[t];
}

__global__ __launch_bounds__(64) void k_scanB(const int* __restrict__ bsum,
                                              int* __restrict__ bbase) {
  __shared__ int s[64];
  int t = threadIdx.x;
  int v = bsum[t];
  s[t] = v;
  __syncthreads();
  for (int d = 1; d < 64; d <<= 1) {
    int x = (t >= d) ? s[t - d] : 0;
    __syncthreads();
    s[t] += x;
    __syncthreads();
  }
  bbase[t] = s[t] - v;
}

__global__ __launch_bounds__(256) void k_scatter(const float* __restrict__ UV,
                                                 int* __restrict__ binoff,
                                                 const int* __restrict__ bbase,
                                                 float4* __restrict__ sorted) {
  int i = blockIdx.x * 256 + threadIdx.x;     // 4096 blocks
  float2 uv = ((const float2*)UV)[i];
  int bin = point_bin(uv.x, uv.y);
  int pos = atomicAdd(&binoff[bin], 1) + bbase[bin >> 8];
  sorted[pos] = make_float4(uv.x, uv.y, __int_as_float(i), 0.0f);
}

// load 8 (or 4, zero-padded) f32s and RTNE-cast to f16 -- replicates the f16 source
__device__ __forceinline__ half8 ld8h(const float* __restrict__ p, bool full) {
  f4 lo = *(const f4*)p;
  f4 hi;
  if (full) hi = *(const f4*)(p + 4);
  else      { hi[0] = 0.f; hi[1] = 0.f; hi[2] = 0.f; hi[3] = 0.f; }
  half8 h;
  h[0] = (_Float16)lo[0]; h[1] = (_Float16)lo[1];
  h[2] = (_Float16)lo[2]; h[3] = (_Float16)lo[3];
  h[4] = (_Float16)hi[0]; h[5] = (_Float16)hi[1];
  h[6] = (_Float16)hi[2]; h[7] = (_Float16)hi[3];
  return h;
}

// K=128 layer, IN-PLACE in G (stride STR0): read-all -> barrier -> write cols 0..127.
// A resident in regs; optionally prefetch next layer's A mid-loop. Bias at epilogue.
// Caller must __syncthreads() after return (write visibility for next phase).
template <bool PF>
__device__ __forceinline__ void layerIP(const half8 (&A)[8], half8 (&An)[8],
    const _Float16* __restrict__ wfn,
    _Float16* G, const float* __restrict__ bp,
    int lane, int nl, int kh, int ot) {
  f4 bf[4];
#pragma unroll
  for (int g = 0; g < 4; ++g)        // issued at phase start, used at epilogue
    bf[g] = *(const f4*)(bp + ot * 32 + 4 * kh + 8 * g);
  f16v a0, a1;
#pragma unroll
  for (int r = 0; r < 16; ++r) { a0[r] = 0.f; a1[r] = 0.f; }
#pragma unroll
  for (int ks = 0; ks < 4; ++ks) {
    half8 B0 = *(const half8*)(G + nl * STR0 + ks * 16 + kh * 8);
    half8 B1 = *(const half8*)(G + (32 + nl) * STR0 + ks * 16 + kh * 8);
    a0 = __builtin_amdgcn_mfma_f32_32x32x16_f16(A[ks], B0, a0, 0, 0, 0);
    a1 = __builtin_amdgcn_mfma_f32_32x32x16_f16(A[ks], B1, a1, 0, 0, 0);
  }
  if constexpr (PF) {                // prefetch next layer's A under MFMA shadow
#pragma unroll
    for (int k2 = 0; k2 < 8; ++k2)
      An[k2] = *(const half8*)(wfn + ((ot * 8 + k2) * 64 + lane) * 8);
  }
#pragma unroll
  for (int ks = 4; ks < 8; ++ks) {
    half8 B0 = *(const half8*)(G + nl * STR0 + ks * 16 + kh * 8);
    half8 B1 = *(const half8*)(G + (32 + nl) * STR0 + ks * 16 + kh * 8);
    a0 = __builtin_amdgcn_mfma_f32_32x32x16_f16(A[ks], B0, a0, 0, 0, 0);
    a1 = __builtin_amdgcn_mfma_f32_32x32x16_f16(A[ks], B1, a1, 0, 0, 0);
  }
  __syncthreads();                   // ALL waves' reads of G done -> safe to overwrite
#pragma unroll
  for (int g = 0; g < 4; ++g) {
    half4v h0, h1;
#pragma unroll
    for (int i = 0; i < 4; ++i) {
      float z0 = a0[4 * g + i] + bf[g][i]; z0 = fmaxf(z0, 0.01f * z0);
      float z1 = a1[4 * g + i] + bf[g][i]; z1 = fmaxf(z1, 0.01f * z1);
      h0[i] = (_Float16)z0; h1[i] = (_Float16)z1;
    }
    int col = ot * 32 + 4 * kh + 8 * g;
    *(half4v*)(G + nl * STR0 + col) = h0;
    *(half4v*)(G + (32 + nl) * STR0 + col) = h1;
  }
}

// MODE: 1 = unsorted; 2 = sorted. f32 features, cast-to-f16 then f16 interp.
template <int MODE>
__global__ __launch_bounds__(256, 6) void k_main(
    const float* __restrict__ UV, const float4* __restrict__ sorted,
    const _Float16* __restrict__ wt, const float* __restrict__ F,
    const float* __restrict__ b0, const float* __restrict__ b1,
    const float* __restrict__ b2, const float* __restrict__ b3,
    const float* __restrict__ b4, float* __restrict__ out) {
  __shared__ _Float16 bufA[TP * STR0] __attribute__((aligned(16)));  // 23552 B
  const int t = threadIdx.x;
  const int lane = t & 63;
  const int nl = lane & 31;
  const int kh = lane >> 5;
  const int ot = t >> 6;       // wave id = out-quarter
  const int pFE = t >> 2;      // FE & L4: 4 threads per point (same mapping!)
  const int sFE = t & 3;

  // ---- L0 A-fragments issued up front ----
  half8 A0[11];
#pragma unroll
  for (int ks = 0; ks < 11; ++ks)
    A0[ks] = *(const half8*)(wt + ((ot * 11 + ks) * 64 + lane) * 8);
  half8 A1[8], A2[8], A3[8];   // filled by the pipeline below

  float U, V;
  int oidx;                    // register-carried to the L4 store (same thread)
  if constexpr (MODE == 2) {
    float4 s4 = sorted[blockIdx.x * TP + pFE];
    U = s4.x; V = s4.y; oidx = __float_as_int(s4.z);
  } else {
    oidx = blockIdx.x * TP + pFE;
    float2 uv = ((const float2*)UV)[oidx];
    U = uv.x; V = uv.y;
  }

  // ---------------- posenc (cols 100..165) + pad zero ----------------
  if (sFE == 0) {
    bufA[pFE * STR0 + 100] = (_Float16)U;
    bufA[pFE * STR0 + 101] = (_Float16)V;
  }
  if (sFE == 1) {
#pragma unroll
    for (int c = 166; c < 176; ++c) bufA[pFE * STR0 + c] = (_Float16)0.0f;
  }

  {
    const float inv2pi = 0.15915494309189535f;
    float Ur = U * inv2pi, Vr = V * inv2pi;
#pragma unroll
    for (int fi = 0; fi < 4; ++fi) {
      int f = 4 * fi + sFE;                  // 4 threads x 4 = 16 freqs
      float kk = (float)(1 << f);
      float ru = kk * Ur; ru -= floorf(ru);  // revolutions in [0,1)
      float rv = kk * Vr; rv -= floorf(rv);
      float su = __builtin_amdgcn_sinf(ru);  // v_sin_f32: sin(2*pi*x)
      float cu = __builtin_amdgcn_cosf(ru);
      float sv = __builtin_amdgcn_sinf(rv);
      float cv = __builtin_amdgcn_cosf(rv);
      int cbase = pFE * STR0 + 102 + 4 * f;
      bufA[cbase + 0] = (_Float16)su;
      bufA[cbase + 1] = (_Float16)sv;
      bufA[cbase + 2] = (_Float16)cu;
      bufA[cbase + 3] = (_Float16)cv;
    }
  }

  // ---- bilinear gather (cols 0..99): f32 load -> f16 cast -> f16 interp ----
  {
    float iu = 511.0f * U, iv = 511.0f * V;
    float fu0 = floorf(iu), fv0 = floorf(iv);
    int iU0 = (int)fu0, iV0 = (int)fv0;
    int iU1 = (int)ceilf(iu), iV1 = (int)ceilf(iv);
    float fu = iu - fu0, fv = iv - fv0;
    float w00 = (1.f - fu) * (1.f - fv);
    float w10 = fu * (1.f - fv);
    float w01 = (1.f - fu) * fv;
    float w11 = fu * fv;
    const float* F00 = F + (size_t)(iU0 * GN + iV0) * 100;
    const float* F01 = F + (size_t)(iU0 * GN + iV1) * 100;
    const float* F10 = F + (size_t)(iU1 * GN + iV0) * 100;
    const float* F11 = F + (size_t)(iU1 * GN + iV1) * 100;
    _Float16 h00 = (_Float16)w00, h01 = (_Float16)w01;
    _Float16 h10 = (_Float16)w10, h11 = (_Float16)w11;
    half8 v00, v01, v10, v11;
#pragma unroll
    for (int e = 0; e < 8; ++e) { v00[e]=h00; v01[e]=h01; v10[e]=h10; v11[e]=h11; }
    for (int j = sFE; j < 13; j += 4) {      // chunks {s, s+4, s+8, s+12}: covers 0..12
      bool full = (j < 12);                  // chunk 12: only cols 96..99 exist
      half8 a = ld8h(F00 + 8 * j, full);
      half8 b = ld8h(F01 + 8 * j, full);
      half8 c = ld8h(F10 + 8 * j, full);
      half8 d = ld8h(F11 + 8 * j, full);
      half8 o = a * v00 + b * v01 + c * v10 + d * v11;  // v_pk_fma_f16
      if (full) {
        *(half8*)&bufA[pFE * STR0 + 8 * j] = o;
      } else {
        half4v o4; o4[0]=o[0]; o4[1]=o[1]; o4[2]=o[2]; o4[3]=o[3];
        *(half4v*)&bufA[pFE * STR0 + 96] = o4;
      }
    }
  }
  __syncthreads();

  // ------- layer 0: K=176 (11 ksteps), in-place bufA: read X, write G1 -------
  {
    f4 bf[4];
#pragma unroll
    for (int g = 0; g < 4; ++g)
      bf[g] = *(const f4*)(b0 + ot * 32 + 4 * kh + 8 * g);
    f16v a0, a1;
#pragma unroll
    for (int r = 0; r < 16; ++r) { a0[r] = 0.f; a1[r] = 0.f; }
#pragma unroll
    for (int ks = 0; ks < 8; ++ks) {
      half8 B0 = *(const half8*)&bufA[nl * STR0 + ks * 16 + kh * 8];
      half8 B1 = *(const half8*)&bufA[(32 + nl) * STR0 + ks * 16 + kh * 8];
      a0 = __builtin_amdgcn_mfma_f32_32x32x16_f16(A0[ks], B0, a0, 0, 0, 0);
      a1 = __builtin_amdgcn_mfma_f32_32x32x16_f16(A0[ks], B1, a1, 0, 0, 0);
    }
#pragma unroll                       // prefetch L1 A under the MFMA shadow
    for (int k2 = 0; k2 < 8; ++k2)
      A1[k2] = *(const half8*)(wt + WOFF1 + ((ot * 8 + k2) * 64 + lane) * 8);
#pragma unroll
    for (int ks = 8; ks < 11; ++ks) {
      half8 B0 = *(const half8*)&bufA[nl * STR0 + ks * 16 + kh * 8];
      half8 B1 = *(const half8*)&bufA[(32 + nl) * STR0 + ks * 16 + kh * 8];
      a0 = __builtin_amdgcn_mfma_f32_32x32x16_f16(A0[ks], B0, a0, 0, 0, 0);
      a1 = __builtin_amdgcn_mfma_f32_32x32x16_f16(A0[ks], B1, a1, 0, 0, 0);
    }
    __syncthreads();                 // all reads of X done -> overwrite cols 0..127
#pragma unroll
    for (int g = 0; g < 4; ++g) {
      half4v h0, h1;
#pragma unroll
      for (int i = 0; i < 4; ++i) {
        float z0 = a0[4 * g + i] + bf[g][i]; z0 = fmaxf(z0, 0.01f * z0);
        float z1 = a1[4 * g + i] + bf[g][i]; z1 = fmaxf(z1, 0.01f * z1);
        h0[i] = (_Float16)z0; h1[i] = (_Float16)z1;
      }
      int col = ot * 32 + 4 * kh + 8 * g;
      *(half4v*)&bufA[nl * STR0 + col] = h0;
      *(half4v*)&bufA[(32 + nl) * STR0 + col] = h1;
    }
  }
  __syncthreads();
  layerIP<true >(A1, A2, wt + WOFF2, bufA, b1, lane, nl, kh, ot);
  __syncthreads();   // L1 writes visible
  layerIP<true >(A2, A3, wt + WOFF3, bufA, b2, lane, nl, kh, ot);
  __syncthreads();   // L2 writes visible
  layerIP<false>(A3, A3, wt,         bufA, b3, lane, nl, kh, ot);
  __syncthreads();   // L3 writes visible -> bufA cols 0..127 hold h3

  // ---------------- layer 4: 128 -> 3, 4 threads/point, packed f16 W4 -------
  {
    const _Float16* h4 = &bufA[pFE * STR0 + sFE * 32];
    const _Float16* w4 = wt + W4OFF + sFE * 96;
    float y0 = 0.f, y1 = 0.f, y2 = 0.f;
#pragma unroll
    for (int c = 0; c < 4; ++c) {
      half8 hv = *(const half8*)(h4 + 8 * c);
      half8 wa = *(const half8*)(w4 + c * 24);
      half8 wb = *(const half8*)(w4 + c * 24 + 8);
      half8 wc = *(const half8*)(w4 + c * 24 + 16);
      _Float16 wf[24];
      *(half8*)&wf[0] = wa; *(half8*)&wf[8] = wb; *(half8*)&wf[16] = wc;
#pragma unroll
      for (int e8 = 0; e8 < 8; ++e8) {
        float vf = (float)hv[e8];
        y0 += vf * (float)wf[e8 * 3 + 0];
        y1 += vf * (float)wf[e8 * 3 + 1];
        y2 += vf * (float)wf[e8 * 3 + 2];
      }
    }
    y0 += __shfl_xor(y0, 1); y0 += __shfl_xor(y0, 2);
    y1 += __shfl_xor(y1, 1); y1 += __shfl_xor(y1, 2);
    y2 += __shfl_xor(y2, 1); y2 += __shfl_xor(y2, 2);
    if (sFE == 0) {
      out[(size_t)oidx * 3 + 0] = y0 + b4[0];
      out[(size_t)oidx * 3 + 1] = y1 + b4[1];
      out[(size_t)oidx * 3 + 2] = y2 + b4[2];
    }
  }
}

extern "C" void kernel_launch(void* const* d_in, const int* in_sizes, int n_in,
                              void* d_out, int out_size, void* d_ws, size_t ws_size,
                              hipStream_t stream) {
  const float* UV  = (const float*)d_in[0];
  const float* FEA = (const float*)d_in[1];
  const float* W0  = (const float*)d_in[2];
  const float* b0  = (const float*)d_in[3];
  const float* W1  = (const float*)d_in[4];
  const float* b1  = (const float*)d_in[5];
  const float* W2  = (const float*)d_in[6];
  const float* b2  = (const float*)d_in[7];
  const float* W3  = (const float*)d_in[8];
  const float* b3  = (const float*)d_in[9];
  const float* W4  = (const float*)d_in[10];
  const float* b4  = (const float*)d_in[11];
  float* out = (float*)d_out;

  char* ws = (char*)d_ws;
  _Float16* wt = (_Float16*)ws;
  int*    hist   = (int*)(ws + 147456);
  int*    binoff = (int*)(ws + 212992);
  int*    bsum   = (int*)(ws + 278528);
  int*    bbase  = (int*)(ws + 278784);
  float4* sorted = (float4*)(ws + 294912);

  const size_t needSort = 294912ull + 16777216ull;   // ~17 MB

  const int nblk = 1048576 / TP;   // 16384

  if (ws_size >= needSort) {
    hipMemsetAsync(hist, 0, 65536, stream);
    k_prep<<<282 + 4096, 256, 0, stream>>>(W0, W1, W2, W3, W4, wt, UV, hist);
    k_scanA<<<64, 256, 0, stream>>>(hist, binoff, bsum);
    k_scanB<<<1, 64, 0, stream>>>(bsum, bbase);
    k_scatter<<<4096, 256, 0, stream>>>(UV, binoff, bbase, sorted);
    k_main<2><<<nblk, 256, 0, stream>>>(UV, sorted, wt, FEA,
                                        b0, b1, b2, b3, b4, out);
  } else {
    k_prep<<<282, 256, 0, stream>>>(W0, W1, W2, W3, W4, wt, UV, nullptr);
    k_main<1><<<nblk, 256, 0, stream>>>(UV, nullptr, wt, FEA,
                                        b0, b1, b2, b3, b4, out);
  }
}

// Round 9
// 500.981 us; speedup vs baseline: 1.3431x; 1.3431x over previous
//
#include <hip/hip_runtime.h>

// ReLU_Feat_Posenc: bilinear gather (512x512x100) + posenc(16 freq) + MLP 166->128x4->3
// R12: fix R11's self-inflicted spill. launch_bounds(256,6) capped VGPR at ~85 (compiler
//      chose 40) << ~140 of live A-fragments -> scratch spill (WRITE 42->631MB, FETCH
//      +300MB, 294->467us). R12 = same single-buffer body with launch_bounds(256,4):
//      compiler gets R9's register freedom (~60 VGPR, no spill); LDS 23552B still
//      PERMITS 6 blocks/CU (24 waves, 75%) if emitted VGPR <= ~85. Worst case compiler
//      uses >85 -> 4 blocks -> exactly R9's 294us. Asymmetric one-line bet.

#define GN    512
#define TP    64    // points per tile
#define STR0  184   // LDS row stride (f16), row = 368 B; X cols 0..175, G cols 0..127

// wt fragment-order offsets (f16 elems)
#define WOFF1 22528
#define WOFF2 38912
#define WOFF3 55296
#define W4OFF 71680  // packed W4: [qt 0..3][kk 0..31][e 0..2] f16 (384 elems)

typedef _Float16 half8  __attribute__((ext_vector_type(8)));
typedef _Float16 half4v __attribute__((ext_vector_type(4)));
typedef float    f4     __attribute__((ext_vector_type(4)));
typedef float    f16v   __attribute__((ext_vector_type(16)));

// ws layout (bytes):
//   0         wt fragment-order f16 (+ packed W4) (reserve 147456)
//   147456    hist    int[16384]
//   212992    binoff  int[16384]
//   278528    bsum    int[64]
//   278784    bbase   int[64]
//   294912    sorted  float4[1048576] (16 MB)   total ~17 MB

// ---------- fused prep: weights+W4 pack | hist ----------
__global__ __launch_bounds__(256) void k_prep(
    const float* __restrict__ W0, const float* __restrict__ W1,
    const float* __restrict__ W2, const float* __restrict__ W3,
    const float* __restrict__ W4, _Float16* __restrict__ wt,
    const float* __restrict__ UV, int* __restrict__ hist) {
  int b = blockIdx.x;
  if (b < 282) {                     // ---- weights into MFMA-fragment order ----
    int t = b * 256 + threadIdx.x;
    if (t >= 72064) return;
    float v;
    if (t < 22528) {                 // L0 frags: ((ot*11+ks)*64+l)*8+j
      int j = t & 7, l = (t >> 3) & 63, g = t >> 9;
      int ks = g % 11;
      int ot = g / 11;
      int k = 16 * ks + 8 * (l >> 5) + j;     // X column
      int n = ot * 32 + (l & 31);             // out channel
      if (k < 100)      v = W0[(66 + k) * 128 + n];   // feat rows of W0
      else if (k < 166) v = W0[(k - 100) * 128 + n];  // UV + posenc rows
      else              v = 0.0f;                     // K pad 166..175
    } else if (t < 71680) {          // L1-3 frags
      int u = t - 22528;
      int layer = u >> 14, r = u & 16383;
      int j = r & 7, l = (r >> 3) & 63, ks = (r >> 9) & 7, ot = r >> 12;
      int k = 16 * ks + 8 * (l >> 5) + j;
      int n = ot * 32 + (l & 31);
      const float* W = (layer == 0) ? W1 : (layer == 1) ? W2 : W3;
      v = W[k * 128 + n];
    } else {                         // packed W4: wt[W4OFF + qt*96 + kk*3 + e]
      int u2 = t - 71680;            // 0..383
      int qt = u2 / 96, r = u2 - 96 * qt;
      int kk = r / 3, e = r - 3 * kk;
      v = W4[(qt * 32 + kk) * 3 + e];
    }
    wt[t] = (_Float16)v;
  } else if (hist != nullptr) {      // ---- histogram (hist pre-zeroed by memset) ----
    int i = (b - 282) * 256 + threadIdx.x;
    float2 uv = ((const float2*)UV)[i];
    int iU0 = (int)floorf(511.0f * uv.x);
    int iV0 = (int)floorf(511.0f * uv.y);
    atomicAdd(&hist[iU0 * 32 + (iV0 >> 4)], 1);
  }
}

__device__ __forceinline__ int point_bin(float U, float V) {
  int iU0 = (int)floorf(511.0f * U);
  int iV0 = (int)floorf(511.0f * V);
  return iU0 * 32 + (iV0 >> 4);
}

__global__ __launch_bounds__(256) void k_scanA(const int* __restrict__ hist,
                                               int* __restrict__ binoff,
                                               int* __restrict__ bsum) {
  __shared__ int s[256];
  int t = threadIdx.x, g = blockIdx.x * 256 + t;   // 64 blocks
  int v = hist[g];
  s[t] = v;
  __syncthreads();
  for (int d = 1; d < 256; d <<= 1) {
    int x = (t >= d) ? s[t - d] : 0;
    __syncthreads();
    s[t] += x;
    __syncthreads();
  }
  binoff[g] = s[t] - v;
  if (t == 255) bsum[blockIdx.x] = s[t];
}

__global__ __launch_bounds__(64) void k_scanB(const int* __restrict__ bsum,
                                              int* __restrict__ bbase) {
  __shared__ int s[64];
  int t = threadIdx.x;
  int v = bsum[t];
  s[t] = v;
  __syncthreads();
  for (int d = 1; d < 64; d <<= 1) {
    int x = (t >= d) ? s[t - d] : 0;
    __syncthreads();
    s[t] += x;
    __syncthreads();
  }
  bbase[t] = s[t] - v;
}

__global__ __launch_bounds__(256) void k_scatter(const float* __restrict__ UV,
                                                 int* __restrict__ binoff,
                                                 const int* __restrict__ bbase,
                                                 float4* __restrict__ sorted) {
  int i = blockIdx.x * 256 + threadIdx.x;     // 4096 blocks
  float2 uv = ((const float2*)UV)[i];
  int bin = point_bin(uv.x, uv.y);
  int pos = atomicAdd(&binoff[bin], 1) + bbase[bin >> 8];
  sorted[pos] = make_float4(uv.x, uv.y, __int_as_float(i), 0.0f);
}

// load 8 (or 4, zero-padded) f32s and RTNE-cast to f16 -- replicates the f16 source
__device__ __forceinline__ half8 ld8h(const float* __restrict__ p, bool full) {
  f4 lo = *(const f4*)p;
  f4 hi;
  if (full) hi = *(const f4*)(p + 4);
  else      { hi[0] = 0.f; hi[1] = 0.f; hi[2] = 0.f; hi[3] = 0.f; }
  half8 h;
  h[0] = (_Float16)lo[0]; h[1] = (_Float16)lo[1];
  h[2] = (_Float16)lo[2]; h[3] = (_Float16)lo[3];
  h[4] = (_Float16)hi[0]; h[5] = (_Float16)hi[1];
  h[6] = (_Float16)hi[2]; h[7] = (_Float16)hi[3];
  return h;
}

// K=128 layer, IN-PLACE in G (stride STR0): read-all -> barrier -> write cols 0..127.
// A resident in regs; optionally prefetch next layer's A mid-loop. Bias at epilogue.
// Caller must __syncthreads() after return (write visibility for next phase).
template <bool PF>
__device__ __forceinline__ void layerIP(const half8 (&A)[8], half8 (&An)[8],
    const _Float16* __restrict__ wfn,
    _Float16* G, const float* __restrict__ bp,
    int lane, int nl, int kh, int ot) {
  f4 bf[4];
#pragma unroll
  for (int g = 0; g < 4; ++g)        // issued at phase start, used at epilogue
    bf[g] = *(const f4*)(bp + ot * 32 + 4 * kh + 8 * g);
  f16v a0, a1;
#pragma unroll
  for (int r = 0; r < 16; ++r) { a0[r] = 0.f; a1[r] = 0.f; }
#pragma unroll
  for (int ks = 0; ks < 4; ++ks) {
    half8 B0 = *(const half8*)(G + nl * STR0 + ks * 16 + kh * 8);
    half8 B1 = *(const half8*)(G + (32 + nl) * STR0 + ks * 16 + kh * 8);
    a0 = __builtin_amdgcn_mfma_f32_32x32x16_f16(A[ks], B0, a0, 0, 0, 0);
    a1 = __builtin_amdgcn_mfma_f32_32x32x16_f16(A[ks], B1, a1, 0, 0, 0);
  }
  if constexpr (PF) {                // prefetch next layer's A under MFMA shadow
#pragma unroll
    for (int k2 = 0; k2 < 8; ++k2)
      An[k2] = *(const half8*)(wfn + ((ot * 8 + k2) * 64 + lane) * 8);
  }
#pragma unroll
  for (int ks = 4; ks < 8; ++ks) {
    half8 B0 = *(const half8*)(G + nl * STR0 + ks * 16 + kh * 8);
    half8 B1 = *(const half8*)(G + (32 + nl) * STR0 + ks * 16 + kh * 8);
    a0 = __builtin_amdgcn_mfma_f32_32x32x16_f16(A[ks], B0, a0, 0, 0, 0);
    a1 = __builtin_amdgcn_mfma_f32_32x32x16_f16(A[ks], B1, a1, 0, 0, 0);
  }
  __syncthreads();                   // ALL waves' reads of G done -> safe to overwrite
#pragma unroll
  for (int g = 0; g < 4; ++g) {
    half4v h0, h1;
#pragma unroll
    for (int i = 0; i < 4; ++i) {
      float z0 = a0[4 * g + i] + bf[g][i]; z0 = fmaxf(z0, 0.01f * z0);
      float z1 = a1[4 * g + i] + bf[g][i]; z1 = fmaxf(z1, 0.01f * z1);
      h0[i] = (_Float16)z0; h1[i] = (_Float16)z1;
    }
    int col = ot * 32 + 4 * kh + 8 * g;
    *(half4v*)(G + nl * STR0 + col) = h0;
    *(half4v*)(G + (32 + nl) * STR0 + col) = h1;
  }
}

// MODE: 1 = unsorted; 2 = sorted. f32 features, cast-to-f16 then f16 interp.
template <int MODE>
__global__ __launch_bounds__(256, 4) void k_main(
    const float* __restrict__ UV, const float4* __restrict__ sorted,
    const _Float16* __restrict__ wt, const float* __restrict__ F,
    const float* __restrict__ b0, const float* __restrict__ b1,
    const float* __restrict__ b2, const float* __restrict__ b3,
    const float* __restrict__ b4, float* __restrict__ out) {
  __shared__ _Float16 bufA[TP * STR0] __attribute__((aligned(16)));  // 23552 B
  const int t = threadIdx.x;
  const int lane = t & 63;
  const int nl = lane & 31;
  const int kh = lane >> 5;
  const int ot = t >> 6;       // wave id = out-quarter
  const int pFE = t >> 2;      // FE & L4: 4 threads per point (same mapping!)
  const int sFE = t & 3;

  // ---- L0 A-fragments issued up front ----
  half8 A0[11];
#pragma unroll
  for (int ks = 0; ks < 11; ++ks)
    A0[ks] = *(const half8*)(wt + ((ot * 11 + ks) * 64 + lane) * 8);
  half8 A1[8], A2[8], A3[8];   // filled by the pipeline below

  float U, V;
  int oidx;                    // register-carried to the L4 store (same thread)
  if constexpr (MODE == 2) {
    float4 s4 = sorted[blockIdx.x * TP + pFE];
    U = s4.x; V = s4.y; oidx = __float_as_int(s4.z);
  } else {
    oidx = blockIdx.x * TP + pFE;
    float2 uv = ((const float2*)UV)[oidx];
    U = uv.x; V = uv.y;
  }

  // ---------------- posenc (cols 100..165) + pad zero ----------------
  if (sFE == 0) {
    bufA[pFE * STR0 + 100] = (_Float16)U;
    bufA[pFE * STR0 + 101] = (_Float16)V;
  }
  if (sFE == 1) {
#pragma unroll
    for (int c = 166; c < 176; ++c) bufA[pFE * STR0 + c] = (_Float16)0.0f;
  }

  {
    const float inv2pi = 0.15915494309189535f;
    float Ur = U * inv2pi, Vr = V * inv2pi;
#pragma unroll
    for (int fi = 0; fi < 4; ++fi) {
      int f = 4 * fi + sFE;                  // 4 threads x 4 = 16 freqs
      float kk = (float)(1 << f);
      float ru = kk * Ur; ru -= floorf(ru);  // revolutions in [0,1)
      float rv = kk * Vr; rv -= floorf(rv);
      float su = __builtin_amdgcn_sinf(ru);  // v_sin_f32: sin(2*pi*x)
      float cu = __builtin_amdgcn_cosf(ru);
      float sv = __builtin_amdgcn_sinf(rv);
      float cv = __builtin_amdgcn_cosf(rv);
      int cbase = pFE * STR0 + 102 + 4 * f;
      bufA[cbase + 0] = (_Float16)su;
      bufA[cbase + 1] = (_Float16)sv;
      bufA[cbase + 2] = (_Float16)cu;
      bufA[cbase + 3] = (_Float16)cv;
    }
  }

  // ---- bilinear gather (cols 0..99): f32 load -> f16 cast -> f16 interp ----
  {
    float iu = 511.0f * U, iv = 511.0f * V;
    float fu0 = floorf(iu), fv0 = floorf(iv);
    int iU0 = (int)fu0, iV0 = (int)fv0;
    int iU1 = (int)ceilf(iu), iV1 = (int)ceilf(iv);
    float fu = iu - fu0, fv = iv - fv0;
    float w00 = (1.f - fu) * (1.f - fv);
    float w10 = fu * (1.f - fv);
    float w01 = (1.f - fu) * fv;
    float w11 = fu * fv;
    const float* F00 = F + (size_t)(iU0 * GN + iV0) * 100;
    const float* F01 = F + (size_t)(iU0 * GN + iV1) * 100;
    const float* F10 = F + (size_t)(iU1 * GN + iV0) * 100;
    const float* F11 = F + (size_t)(iU1 * GN + iV1) * 100;
    _Float16 h00 = (_Float16)w00, h01 = (_Float16)w01;
    _Float16 h10 = (_Float16)w10, h11 = (_Float16)w11;
    half8 v00, v01, v10, v11;
#pragma unroll
    for (int e = 0; e < 8; ++e) { v00[e]=h00; v01[e]=h01; v10[e]=h10; v11[e]=h11; }
    for (int j = sFE; j < 13; j += 4) {      // chunks {s, s+4, s+8, s+12}: covers 0..12
      bool full = (j < 12);                  // chunk 12: only cols 96..99 exist
      half8 a = ld8h(F00 + 8 * j, full);
      half8 b = ld8h(F01 + 8 * j, full);
      half8 c = ld8h(F10 + 8 * j, full);
      half8 d = ld8h(F11 + 8 * j, full);
      half8 o = a * v00 + b * v01 + c * v10 + d * v11;  // v_pk_fma_f16
      if (full) {
        *(half8*)&bufA[pFE * STR0 + 8 * j] = o;
      } else {
        half4v o4; o4[0]=o[0]; o4[1]=o[1]; o4[2]=o[2]; o4[3]=o[3];
        *(half4v*)&bufA[pFE * STR0 + 96] = o4;
      }
    }
  }
  __syncthreads();

  // ------- layer 0: K=176 (11 ksteps), in-place bufA: read X, write G1 -------
  {
    f4 bf[4];
#pragma unroll
    for (int g = 0; g < 4; ++g)
      bf[g] = *(const f4*)(b0 + ot * 32 + 4 * kh + 8 * g);
    f16v a0, a1;
#pragma unroll
    for (int r = 0; r < 16; ++r) { a0[r] = 0.f; a1[r] = 0.f; }
#pragma unroll
    for (int ks = 0; ks < 8; ++ks) {
      half8 B0 = *(const half8*)&bufA[nl * STR0 + ks * 16 + kh * 8];
      half8 B1 = *(const half8*)&bufA[(32 + nl) * STR0 + ks * 16 + kh * 8];
      a0 = __builtin_amdgcn_mfma_f32_32x32x16_f16(A0[ks], B0, a0, 0, 0, 0);
      a1 = __builtin_amdgcn_mfma_f32_32x32x16_f16(A0[ks], B1, a1, 0, 0, 0);
    }
#pragma unroll                       // prefetch L1 A under the MFMA shadow
    for (int k2 = 0; k2 < 8; ++k2)
      A1[k2] = *(const half8*)(wt + WOFF1 + ((ot * 8 + k2) * 64 + lane) * 8);
#pragma unroll
    for (int ks = 8; ks < 11; ++ks) {
      half8 B0 = *(const half8*)&bufA[nl * STR0 + ks * 16 + kh * 8];
      half8 B1 = *(const half8*)&bufA[(32 + nl) * STR0 + ks * 16 + kh * 8];
      a0 = __builtin_amdgcn_mfma_f32_32x32x16_f16(A0[ks], B0, a0, 0, 0, 0);
      a1 = __builtin_amdgcn_mfma_f32_32x32x16_f16(A0[ks], B1, a1, 0, 0, 0);
    }
    __syncthreads();                 // all reads of X done -> overwrite cols 0..127
#pragma unroll
    for (int g = 0; g < 4; ++g) {
      half4v h0, h1;
#pragma unroll
      for (int i = 0; i < 4; ++i) {
        float z0 = a0[4 * g + i] + bf[g][i]; z0 = fmaxf(z0, 0.01f * z0);
        float z1 = a1[4 * g + i] + bf[g][i]; z1 = fmaxf(z1, 0.01f * z1);
        h0[i] = (_Float16)z0; h1[i] = (_Float16)z1;
      }
      int col = ot * 32 + 4 * kh + 8 * g;
      *(half4v*)&bufA[nl * STR0 + col] = h0;
      *(half4v*)&bufA[(32 + nl) * STR0 + col] = h1;
    }
  }
  __syncthreads();
  layerIP<true >(A1, A2, wt + WOFF2, bufA, b1, lane, nl, kh, ot);
  __syncthreads();   // L1 writes visible
  layerIP<true >(A2, A3, wt + WOFF3, bufA, b2, lane, nl, kh, ot);
  __syncthreads();   // L2 writes visible
  layerIP<false>(A3, A3, wt,         bufA, b3, lane, nl, kh, ot);
  __syncthreads();   // L3 writes visible -> bufA cols 0..127 hold h3

  // ---------------- layer 4: 128 -> 3, 4 threads/point, packed f16 W4 -------
  {
    const _Float16* h4 = &bufA[pFE * STR0 + sFE * 32];
    const _Float16* w4 = wt + W4OFF + sFE * 96;
    float y0 = 0.f, y1 = 0.f, y2 = 0.f;
#pragma unroll
    for (int c = 0; c < 4; ++c) {
      half8 hv = *(const half8*)(h4 + 8 * c);
      half8 wa = *(const half8*)(w4 + c * 24);
      half8 wb = *(const half8*)(w4 + c * 24 + 8);
      half8 wc = *(const half8*)(w4 + c * 24 + 16);
      _Float16 wf[24];
      *(half8*)&wf[0] = wa; *(half8*)&wf[8] = wb; *(half8*)&wf[16] = wc;
#pragma unroll
      for (int e8 = 0; e8 < 8; ++e8) {
        float vf = (float)hv[e8];
        y0 += vf * (float)wf[e8 * 3 + 0];
        y1 += vf * (float)wf[e8 * 3 + 1];
        y2 += vf * (float)wf[e8 * 3 + 2];
      }
    }
    y0 += __shfl_xor(y0, 1); y0 += __shfl_xor(y0, 2);
    y1 += __shfl_xor(y1, 1); y1 += __shfl_xor(y1, 2);
    y2 += __shfl_xor(y2, 1); y2 += __shfl_xor(y2, 2);
    if (sFE == 0) {
      out[(size_t)oidx * 3 + 0] = y0 + b4[0];
      out[(size_t)oidx * 3 + 1] = y1 + b4[1];
      out[(size_t)oidx * 3 + 2] = y2 + b4[2];
    }
  }
}

extern "C" void kernel_launch(void* const* d_in, const int* in_sizes, int n_in,
                              void* d_out, int out_size, void* d_ws, size_t ws_size,
                              hipStream_t stream) {
  const float* UV  = (const float*)d_in[0];
  const float* FEA = (const float*)d_in[1];
  const float* W0  = (const float*)d_in[2];
  const float* b0  = (const float*)d_in[3];
  const float* W1  = (const float*)d_in[4];
  const float* b1  = (const float*)d_in[5];
  const float* W2  = (const float*)d_in[6];
  const float* b2  = (const float*)d_in[7];
  const float* W3  = (const float*)d_in[8];
  const float* b3  = (const float*)d_in[9];
  const float* W4  = (const float*)d_in[10];
  const float* b4  = (const float*)d_in[11];
  float* out = (float*)d_out;

  char* ws = (char*)d_ws;
  _Float16* wt = (_Float16*)ws;
  int*    hist   = (int*)(ws + 147456);
  int*    binoff = (int*)(ws + 212992);
  int*    bsum   = (int*)(ws + 278528);
  int*    bbase  = (int*)(ws + 278784);
  float4* sorted = (float4*)(ws + 294912);

  const size_t needSort = 294912ull + 16777216ull;   // ~17 MB

  const int nblk = 1048576 / TP;   // 16384

  if (ws_size >= needSort) {
    hipMemsetAsync(hist, 0, 65536, stream);
    k_prep<<<282 + 4096, 256, 0, stream>>>(W0, W1, W2, W3, W4, wt, UV, hist);
    k_scanA<<<64, 256, 0, stream>>>(hist, binoff, bsum);
    k_scanB<<<1, 64, 0, stream>>>(bsum, bbase);
    k_scatter<<<4096, 256, 0, stream>>>(UV, binoff, bbase, sorted);
    k_main<2><<<nblk, 256, 0, stream>>>(UV, sorted, wt, FEA,
                                        b0, b1, b2, b3, b4, out);
  } else {
    k_prep<<<282, 256, 0, stream>>>(W0, W1, W2, W3, W4, wt, UV, nullptr);
    k_main<1><<<nblk, 256, 0, stream>>>(UV, nullptr, wt, FEA,
                                        b0, b1, b2, b3, b4, out);
  }
}